// Round 2
// baseline (129.056 us; speedup 1.0000x reference)
//
#include <hip/hip_runtime.h>

#define L 21
#define C0 32
#define C1 32
#define IN_DIM 7
#define GHIST 256
#define PAD 64

// ---------------- K1: per-block histogram of idx ----------------
__global__ __launch_bounds__(256) void k_hist(const int* __restrict__ idx, int E,
                                              int* __restrict__ blockCounts) {
  __shared__ int h[L];
  int tid = threadIdx.x;
  if (tid < L) h[tid] = 0;
  __syncthreads();
  int per = (E + GHIST - 1) / GHIST;
  int s = blockIdx.x * per;
  int e = min(E, s + per);
  for (int i = s + tid; i < e; i += blockDim.x)
    atomicAdd(&h[idx[i]], 1);
  __syncthreads();
  if (tid < L) blockCounts[blockIdx.x * L + tid] = h[tid];
}

// ---------------- K2: scan, padded bases, per-block cursors, waveL, pad perm ---
__global__ __launch_bounds__(256) void k_scan(const int* __restrict__ blockCounts,
                                              int* __restrict__ cursor,
                                              int* __restrict__ perm,
                                              int* __restrict__ waveL,
                                              int Wmax) {
  __shared__ int tot[L];
  __shared__ int base[L + 1];
  int tid = threadIdx.x;
  if (tid < L) {
    int s = 0;
#pragma unroll 8
    for (int b = 0; b < GHIST; b++) s += blockCounts[b * L + tid];
    tot[tid] = s;
  }
  __syncthreads();
  if (tid == 0) {
    int a = 0;
    for (int l = 0; l < L; l++) { base[l] = a; a += (tot[l] + PAD - 1) & ~(PAD - 1); }
    base[L] = a;
  }
  __syncthreads();
  if (tid < L) {
    int a = base[tid];
#pragma unroll 8
    for (int b = 0; b < GHIST; b++) {
      cursor[b * L + tid] = a;
      a += blockCounts[b * L + tid];
    }
  }
  // fill padding slots of perm with -1
  for (int l = 0; l < L; l++) {
    int s = base[l] + tot[l];
    int e = base[l + 1];
    for (int i = s + tid; i < e; i += blockDim.x) perm[i] = -1;
  }
  __syncthreads();
  int W = base[L] >> 6;  // number of real waves
  for (int w = tid; w < Wmax; w += blockDim.x) {
    int lv = -1;
    if (w < W) {
      int pos = w << 6;
      for (int l = 0; l < L; l++)
        if (pos >= base[l] && pos < base[l + 1]) lv = l;
    }
    waveL[w] = lv;
  }
}

// ---------------- K3: scatter edge ids into bucketed perm + inverse (rank) ----
__global__ __launch_bounds__(256) void k_scatter(const int* __restrict__ idx, int E,
                                                 const int* __restrict__ cursor,
                                                 int* __restrict__ perm,
                                                 int* __restrict__ rank) {
  __shared__ int cur[L];
  int tid = threadIdx.x;
  if (tid < L) cur[tid] = cursor[blockIdx.x * L + tid];
  __syncthreads();
  int per = (E + GHIST - 1) / GHIST;
  int s = blockIdx.x * per;
  int e = min(E, s + per);
  for (int i = s + tid; i < e; i += blockDim.x) {
    int l = idx[i];
    int pos = atomicAdd(&cur[l], 1);
    perm[pos] = i;
    rank[i] = pos;
  }
}

// ---------------- K3b: gather input rows into bucketed, 32B-padded xb ---------
// Coalesced-ish reads (consecutive lanes read consecutive rows, full line reuse),
// scattered-but-dense 32B writes (fire-and-forget, latency tolerant).
__global__ __launch_bounds__(256) void k_gather(const float* __restrict__ inp,
                                                const int* __restrict__ rank, int E,
                                                float* __restrict__ xb) {
  int i = blockIdx.x * blockDim.x + threadIdx.x;
  if (i >= E) return;
  int r = rank[i];
  const float* row = inp + (size_t)i * IN_DIM;
  float4 a, b;
  a.x = row[0]; a.y = row[1]; a.z = row[2]; a.w = row[3];
  b.x = row[4]; b.y = row[5]; b.z = row[6]; b.w = 0.f;
  float4* dst = (float4*)(xb + (size_t)r * 8);
  dst[0] = a;
  dst[1] = b;
}

// ---------------- K4: compute from xb. Wave-uniform l -> scalar weights -------
__global__ __launch_bounds__(256) void k_compute(const float* __restrict__ xb,
                                                 const float* __restrict__ W0g,
                                                 const float* __restrict__ b0g,
                                                 const float* __restrict__ W1g,
                                                 const float* __restrict__ b1g,
                                                 const int* __restrict__ perm,
                                                 const int* __restrict__ waveL,
                                                 float* __restrict__ out,
                                                 int Wmax) {
  int gid = blockIdx.x * blockDim.x + threadIdx.x;
  int wave = gid >> 6;
  if (wave >= Wmax) return;
  int l = waveL[wave];
  if (l < 0) return;                       // wave entirely past data (uniform)
  l = __builtin_amdgcn_readfirstlane(l);   // force SGPR -> scalar weight loads

  const float4* xrow = (const float4*)(xb + (size_t)gid * 8);
  float4 xa = xrow[0];
  float4 xc = xrow[1];
  float x[IN_DIM] = {xa.x, xa.y, xa.z, xa.w, xc.x, xc.y, xc.z};

  const float* w0 = W0g + l * (IN_DIM * C0);
  const float* B0 = b0g + l * C0;
  const float* w1 = W1g + l * (C0 * C1);
  const float* B1 = b1g + l * C1;

  float h[C0];
#pragma unroll
  for (int c = 0; c < C0; c++) h[c] = B0[c];
#pragma unroll
  for (int k = 0; k < IN_DIM; k++) {
#pragma unroll
    for (int c = 0; c < C0; c++) h[c] = fmaf(x[k], w0[k * C0 + c], h[c]);
  }
#pragma unroll
  for (int c = 0; c < C0; c++) h[c] = h[c] >= 0.f ? h[c] : 0.2f * h[c];

  float o[C1];
#pragma unroll
  for (int c = 0; c < C1; c++) o[c] = B1[c];
#pragma unroll
  for (int k = 0; k < C0; k++) {
#pragma unroll
    for (int c = 0; c < C1; c++) o[c] = fmaf(h[k], w1[k * C1 + c], o[c]);
  }
#pragma unroll
  for (int c = 0; c < C1; c++) o[c] = o[c] >= 0.f ? o[c] : 0.2f * o[c];

  int p = perm[gid];
  if (p >= 0) {
    float4* orow = (float4*)(out + (size_t)p * C1);
#pragma unroll
    for (int j = 0; j < 8; j++) {
      float4 v = {o[j * 4], o[j * 4 + 1], o[j * 4 + 2], o[j * 4 + 3]};
      orow[j] = v;
    }
  }
}

// ---------------- Fallback compute (reads inp directly) if ws too small -------
__global__ __launch_bounds__(256) void k_compute_direct(const float* __restrict__ inp,
                                                        const float* __restrict__ W0g,
                                                        const float* __restrict__ b0g,
                                                        const float* __restrict__ W1g,
                                                        const float* __restrict__ b1g,
                                                        const int* __restrict__ perm,
                                                        const int* __restrict__ waveL,
                                                        float* __restrict__ out,
                                                        int Wmax) {
  int gid = blockIdx.x * blockDim.x + threadIdx.x;
  int wave = gid >> 6;
  if (wave >= Wmax) return;
  int l = waveL[wave];
  if (l < 0) return;
  l = __builtin_amdgcn_readfirstlane(l);

  int p = perm[gid];
  bool valid = p >= 0;
  int pp = valid ? p : 0;

  const float* xrow = inp + (size_t)pp * IN_DIM;
  float x[IN_DIM];
#pragma unroll
  for (int k = 0; k < IN_DIM; k++) x[k] = xrow[k];

  const float* w0 = W0g + l * (IN_DIM * C0);
  const float* B0 = b0g + l * C0;
  const float* w1 = W1g + l * (C0 * C1);
  const float* B1 = b1g + l * C1;

  float h[C0];
#pragma unroll
  for (int c = 0; c < C0; c++) h[c] = B0[c];
#pragma unroll
  for (int k = 0; k < IN_DIM; k++) {
#pragma unroll
    for (int c = 0; c < C0; c++) h[c] = fmaf(x[k], w0[k * C0 + c], h[c]);
  }
#pragma unroll
  for (int c = 0; c < C0; c++) h[c] = h[c] >= 0.f ? h[c] : 0.2f * h[c];

  float o[C1];
#pragma unroll
  for (int c = 0; c < C1; c++) o[c] = B1[c];
#pragma unroll
  for (int k = 0; k < C0; k++) {
#pragma unroll
    for (int c = 0; c < C1; c++) o[c] = fmaf(h[k], w1[k * C1 + c], o[c]);
  }
  if (valid) {
    float* orow = out + (size_t)pp * C1;
#pragma unroll
    for (int j = 0; j < 8; j++) {
      float a0 = o[j * 4],     a1 = o[j * 4 + 1];
      float a2 = o[j * 4 + 2], a3 = o[j * 4 + 3];
      a0 = a0 >= 0.f ? a0 : 0.2f * a0;
      a1 = a1 >= 0.f ? a1 : 0.2f * a1;
      a2 = a2 >= 0.f ? a2 : 0.2f * a2;
      a3 = a3 >= 0.f ? a3 : 0.2f * a3;
      float4 v = {a0, a1, a2, a3};
      *(float4*)(orow + j * 4) = v;
    }
  }
}

extern "C" void kernel_launch(void* const* d_in, const int* in_sizes, int n_in,
                              void* d_out, int out_size, void* d_ws, size_t ws_size,
                              hipStream_t stream) {
  const float* inp = (const float*)d_in[0];
  const int* idx   = (const int*)d_in[1];
  const float* W0  = (const float*)d_in[2];
  const float* b0  = (const float*)d_in[3];
  const float* W1  = (const float*)d_in[4];
  const float* b1  = (const float*)d_in[5];
  float* out = (float*)d_out;
  int E = in_sizes[1];

  int Wmax = (E + L * PAD + 63) >> 6;  // upper bound on padded wave count
  int slots = Wmax * 64;

  int* ws = (int*)d_ws;
  int* blockCounts = ws;                       // GHIST*L
  int* cursor      = blockCounts + GHIST * L;  // GHIST*L
  int* waveL       = cursor + GHIST * L;       // Wmax
  int* perm        = waveL + Wmax;             // slots
  int* rank        = perm + slots;             // E
  size_t ints = (size_t)2 * GHIST * L + Wmax + slots + E;
  ints = (ints + 3) & ~(size_t)3;              // 16B-align xb
  float* xb = (float*)(ws + ints);             // slots * 8 floats
  size_t need = ints * 4 + (size_t)slots * 8 * 4;
  bool use_xb = ws_size >= need;

  k_hist<<<GHIST, 256, 0, stream>>>(idx, E, blockCounts);
  k_scan<<<1, 256, 0, stream>>>(blockCounts, cursor, perm, waveL, Wmax);
  k_scatter<<<GHIST, 256, 0, stream>>>(idx, E, cursor, perm, rank);

  if (use_xb) {
    k_gather<<<(E + 255) / 256, 256, 0, stream>>>(inp, rank, E, xb);
    k_compute<<<(slots + 255) / 256, 256, 0, stream>>>(xb, W0, b0, W1, b1,
                                                       perm, waveL, out, Wmax);
  } else {
    k_compute_direct<<<(slots + 255) / 256, 256, 0, stream>>>(inp, W0, b0, W1, b1,
                                                              perm, waveL, out, Wmax);
  }
}

// Round 3
// 94.007 us; speedup vs baseline: 1.3728x; 1.3728x over previous
//
#include <hip/hip_runtime.h>

#define L 21
#define C0 32
#define C1 32
#define IN_DIM 7
#define GHIST 256
#define BPAD 256  // bucket padding -> every 256-thread block is layer-uniform

// ---------------- K1: per-block histogram of idx ----------------
__global__ __launch_bounds__(256) void k_hist(const int* __restrict__ idx, int E,
                                              int* __restrict__ blockCounts) {
  __shared__ int h[L];
  int tid = threadIdx.x;
  if (tid < L) h[tid] = 0;
  __syncthreads();
  int per = (E + GHIST - 1) / GHIST;
  int s = blockIdx.x * per;
  int e = min(E, s + per);
  for (int i = s + tid; i < e; i += blockDim.x)
    atomicAdd(&h[idx[i]], 1);
  __syncthreads();
  if (tid < L) blockCounts[blockIdx.x * L + tid] = h[tid];
}

// ---------------- K2: totals, 256-padded bases, per-block cursors, blockL -----
__global__ __launch_bounds__(256) void k_scan(const int* __restrict__ blockCounts,
                                              int* __restrict__ cursor,
                                              int* __restrict__ endArr,
                                              int* __restrict__ blockL,
                                              int nBlk) {
  __shared__ int tot[L];
  __shared__ int base[L + 1];
  int tid = threadIdx.x;
  if (tid < L) {
    int s = 0;
#pragma unroll 8
    for (int b = 0; b < GHIST; b++) s += blockCounts[b * L + tid];
    tot[tid] = s;
  }
  __syncthreads();
  if (tid == 0) {
    int a = 0;
    for (int l = 0; l < L; l++) { base[l] = a; a += (tot[l] + BPAD - 1) & ~(BPAD - 1); }
    base[L] = a;
  }
  __syncthreads();
  if (tid < L) {
    int a = base[tid];
#pragma unroll 8
    for (int b = 0; b < GHIST; b++) {
      cursor[b * L + tid] = a;
      a += blockCounts[b * L + tid];
    }
    endArr[tid] = base[tid] + tot[tid];
  }
  __syncthreads();
  // per-compute-block layer id (-1 = fully past data); blocks never straddle buckets
  for (int blk = tid; blk < nBlk; blk += 256) {
    int pos = blk * 256;
    int lv = -1;
#pragma unroll
    for (int l = 0; l < L; l++)
      if (pos >= base[l] && pos < base[l + 1]) lv = l;
    blockL[blk] = lv;
  }
}

// ---------------- K3: scatter edge ids + gather input rows (fused) ------------
__global__ __launch_bounds__(256) void k_scatter(const int* __restrict__ idx,
                                                 const float* __restrict__ inp, int E,
                                                 const int* __restrict__ cursor,
                                                 int* __restrict__ perm,
                                                 float* __restrict__ xb) {
  __shared__ int cur[L];
  int tid = threadIdx.x;
  if (tid < L) cur[tid] = cursor[blockIdx.x * L + tid];
  __syncthreads();
  int per = (E + GHIST - 1) / GHIST;
  int s = blockIdx.x * per;
  int e = min(E, s + per);
  for (int i = s + tid; i < e; i += blockDim.x) {
    int l = idx[i];
    int pos = atomicAdd(&cur[l], 1);
    perm[pos] = i;
    const float* row = inp + (size_t)i * IN_DIM;
    float4 a, b;
    a.x = row[0]; a.y = row[1]; a.z = row[2]; a.w = row[3];
    b.x = row[4]; b.y = row[5]; b.z = row[6]; b.w = 0.f;
    float4* dst = (float4*)(xb + (size_t)pos * 8);
    dst[0] = a;
    dst[1] = b;
  }
}

// ---------------- K4: compute. Block-uniform l; LDS-transposed coalesced store
template <bool USE_XB>
__global__ __launch_bounds__(256) void k_compute(const float* __restrict__ xb,
                                                 const float* __restrict__ inp,
                                                 const float* __restrict__ W0g,
                                                 const float* __restrict__ b0g,
                                                 const float* __restrict__ W1g,
                                                 const float* __restrict__ b1g,
                                                 const int* __restrict__ perm,
                                                 const int* __restrict__ blockL,
                                                 const int* __restrict__ endArr,
                                                 float* __restrict__ out) {
  int l = blockL[blockIdx.x];
  if (l < 0) return;  // uniform across block: no sync skipped
  l = __builtin_amdgcn_readfirstlane(l);
  int end = __builtin_amdgcn_readfirstlane(endArr[l]);

  int T = threadIdx.x;
  int blockbase = blockIdx.x * 256;
  int slot = blockbase + T;

  // ---- load input row (padding slots read garbage; never stored) ----
  float x[IN_DIM];
  if (USE_XB) {
    const float4* xrow = (const float4*)(xb + (size_t)slot * 8);
    float4 xa = xrow[0], xc = xrow[1];
    x[0] = xa.x; x[1] = xa.y; x[2] = xa.z; x[3] = xa.w;
    x[4] = xc.x; x[5] = xc.y; x[6] = xc.z;
  } else {
    int p0 = slot < end ? perm[slot] : 0;
    const float* row = inp + (size_t)p0 * IN_DIM;
#pragma unroll
    for (int k = 0; k < IN_DIM; k++) x[k] = row[k];
  }

  const float* w0 = W0g + l * (IN_DIM * C0);
  const float* B0 = b0g + l * C0;
  const float* w1 = W1g + l * (C0 * C1);
  const float* B1 = b1g + l * C1;

  float h[C0];
#pragma unroll
  for (int c = 0; c < C0; c++) h[c] = B0[c];
#pragma unroll
  for (int k = 0; k < IN_DIM; k++) {
#pragma unroll
    for (int c = 0; c < C0; c++) h[c] = fmaf(x[k], w0[k * C0 + c], h[c]);
  }
#pragma unroll
  for (int c = 0; c < C0; c++) h[c] = h[c] >= 0.f ? h[c] : 0.2f * h[c];

  float o[C1];
#pragma unroll
  for (int c = 0; c < C1; c++) o[c] = B1[c];
#pragma unroll
  for (int k = 0; k < C0; k++) {
#pragma unroll
    for (int c = 0; c < C1; c++) o[c] = fmaf(h[k], w1[k * C1 + c], o[c]);
  }
#pragma unroll
  for (int c = 0; c < C1; c++) o[c] = o[c] >= 0.f ? o[c] : 0.2f * o[c];

  // ---- LDS transpose epilogue: XOR-swizzled [256][32] f32 tile ----
  __shared__ float obuf[256 * 32];
#pragma unroll
  for (int cq = 0; cq < 32; cq += 4) {
    int ad = T * 32 + (cq ^ ((T & 7) << 2));
    float4 v = {o[cq], o[cq + 1], o[cq + 2], o[cq + 3]};
    *(float4*)&obuf[ad] = v;
  }
  __syncthreads();
  // 8 threads per row -> 128B contiguous bursts per row
  int cq = (T & 7) * 4;
#pragma unroll
  for (int j = 0; j < 8; j++) {
    int r = j * 32 + (T >> 3);
    int slot_r = blockbase + r;
    if (slot_r < end) {
      int p = perm[slot_r];
      float4 v = *(const float4*)&obuf[r * 32 + (cq ^ ((r & 7) << 2))];
      *(float4*)(out + (size_t)p * C1 + cq) = v;
    }
  }
}

extern "C" void kernel_launch(void* const* d_in, const int* in_sizes, int n_in,
                              void* d_out, int out_size, void* d_ws, size_t ws_size,
                              hipStream_t stream) {
  const float* inp = (const float*)d_in[0];
  const int* idx   = (const int*)d_in[1];
  const float* W0  = (const float*)d_in[2];
  const float* b0  = (const float*)d_in[3];
  const float* W1  = (const float*)d_in[4];
  const float* b1  = (const float*)d_in[5];
  float* out = (float*)d_out;
  int E = in_sizes[1];

  int nBlk = (E + 255) / 256 + L;  // upper bound on padded 256-blocks
  size_t slots = (size_t)nBlk * 256;

  int* ws = (int*)d_ws;
  int* blockCounts = ws;                       // GHIST*L
  int* cursor      = blockCounts + GHIST * L;  // GHIST*L
  int* endArr      = cursor + GHIST * L;       // L
  int* blockL      = endArr + L;               // nBlk
  int* perm        = blockL + nBlk;            // slots
  size_t ints = (size_t)2 * GHIST * L + L + nBlk + slots;
  ints = (ints + 3) & ~(size_t)3;              // 16B-align xb
  float* xb = (float*)(ws + ints);             // slots * 8 floats
  size_t need = ints * 4 + slots * 8 * 4;
  bool use_xb = ws_size >= need;

  k_hist<<<GHIST, 256, 0, stream>>>(idx, E, blockCounts);
  k_scan<<<1, 256, 0, stream>>>(blockCounts, cursor, endArr, blockL, nBlk);

  if (use_xb) {
    k_scatter<<<GHIST, 256, 0, stream>>>(idx, inp, E, cursor, perm, xb);
    k_compute<true><<<nBlk, 256, 0, stream>>>(xb, inp, W0, b0, W1, b1,
                                              perm, blockL, endArr, out);
  } else {
    // slim fallback: no xb; scattered loads via perm (still coalesced stores)
    k_scatter<<<GHIST, 256, 0, stream>>>(idx, inp, E, cursor, perm, xb);
    k_compute<false><<<nBlk, 256, 0, stream>>>(nullptr, inp, W0, b0, W1, b1,
                                               perm, blockL, endArr, out);
  }
}

// Round 4
// 89.537 us; speedup vs baseline: 1.4414x; 1.0499x over previous
//
#include <hip/hip_runtime.h>

#define L 21
#define C0 32
#define C1 32
#define IN_DIM 7
#define GHIST 256
#define BPAD 256  // bucket padding -> every 256-thread block is layer-uniform

// ---------------- K1: per-block histogram of idx ----------------
__global__ __launch_bounds__(256) void k_hist(const int* __restrict__ idx, int E,
                                              int* __restrict__ blockCounts) {
  __shared__ int h[L];
  int tid = threadIdx.x;
  if (tid < L) h[tid] = 0;
  __syncthreads();
  int per = (E + GHIST - 1) / GHIST;
  int s = blockIdx.x * per;
  int e = min(E, s + per);
  for (int i = s + tid; i < e; i += blockDim.x)
    atomicAdd(&h[idx[i]], 1);
  __syncthreads();
  if (tid < L) blockCounts[blockIdx.x * L + tid] = h[tid];
}

// ---------------- K2: totals, 256-padded bases, per-block cursors -------------
__global__ __launch_bounds__(256) void k_scan(const int* __restrict__ blockCounts,
                                              int* __restrict__ cursor,
                                              int* __restrict__ endArr,
                                              int* __restrict__ baseArr) {
  __shared__ int tot[L];
  __shared__ int base[L + 1];
  int tid = threadIdx.x;
  if (tid < L) {
    int s = 0;
#pragma unroll 8
    for (int b = 0; b < GHIST; b++) s += blockCounts[b * L + tid];
    tot[tid] = s;
  }
  __syncthreads();
  if (tid == 0) {
    int a = 0;
    for (int l = 0; l < L; l++) { base[l] = a; a += (tot[l] + BPAD - 1) & ~(BPAD - 1); }
    base[L] = a;
  }
  __syncthreads();
  if (tid < L) {
    int a = base[tid];
#pragma unroll 8
    for (int b = 0; b < GHIST; b++) {
      cursor[b * L + tid] = a;
      a += blockCounts[b * L + tid];
    }
    endArr[tid] = base[tid] + tot[tid];
  }
  if (tid <= L) baseArr[tid] = base[tid];
}

// ---------------- K3: scatter edge ids + gather input rows (fused) ------------
__global__ __launch_bounds__(256) void k_scatter(const int* __restrict__ idx,
                                                 const float* __restrict__ inp, int E,
                                                 const int* __restrict__ cursor,
                                                 int* __restrict__ perm,
                                                 float* __restrict__ xb) {
  __shared__ int cur[L];
  int tid = threadIdx.x;
  if (tid < L) cur[tid] = cursor[blockIdx.x * L + tid];
  __syncthreads();
  int per = (E + GHIST - 1) / GHIST;
  int s = blockIdx.x * per;
  int e = min(E, s + per);
  for (int i = s + tid; i < e; i += blockDim.x) {
    int l = idx[i];
    int pos = atomicAdd(&cur[l], 1);
    perm[pos] = i;
    const float* row = inp + (size_t)i * IN_DIM;
    float4 a, b;
    a.x = row[0]; a.y = row[1]; a.z = row[2]; a.w = row[3];
    b.x = row[4]; b.y = row[5]; b.z = row[6]; b.w = 0.f;
    float4* dst = (float4*)(xb + (size_t)pos * 8);
    dst[0] = a;
    dst[1] = b;
  }
}

// ---------------- K4: compute. Block-uniform l; 8KB chunked coalesced epilogue
template <bool USE_XB>
__global__ __launch_bounds__(256) void k_compute(const float* __restrict__ xb,
                                                 const float* __restrict__ inp,
                                                 const float* __restrict__ W0g,
                                                 const float* __restrict__ b0g,
                                                 const float* __restrict__ W1g,
                                                 const float* __restrict__ b1g,
                                                 const int* __restrict__ perm,
                                                 const int* __restrict__ baseArr,
                                                 const int* __restrict__ endArr,
                                                 float* __restrict__ out) {
  int T = threadIdx.x;
  int lane = T & 63;
  int blockbase = blockIdx.x << 8;

  // derive this block's layer from baseArr (blocks never straddle buckets)
  int bv = baseArr[lane <= L ? lane : L];
  unsigned long long m = __ballot((lane <= L) && (blockbase >= bv));
  int l = __popcll(m) - 1;
  if (l >= L) return;  // past all data (uniform across block)
  l = __builtin_amdgcn_readfirstlane(l);
  int end = __builtin_amdgcn_readfirstlane(endArr[l]);

  int slot = blockbase + T;

  // ---- load input row (padding slots read garbage; never stored) ----
  float x[IN_DIM];
  if (USE_XB) {
    const float4* xrow = (const float4*)(xb + (size_t)slot * 8);
    float4 xa = xrow[0], xc = xrow[1];
    x[0] = xa.x; x[1] = xa.y; x[2] = xa.z; x[3] = xa.w;
    x[4] = xc.x; x[5] = xc.y; x[6] = xc.z;
  } else {
    int p0 = slot < end ? perm[slot] : 0;
    const float* row = inp + (size_t)p0 * IN_DIM;
#pragma unroll
    for (int k = 0; k < IN_DIM; k++) x[k] = row[k];
  }

  const float* w0 = W0g + l * (IN_DIM * C0);
  const float* B0 = b0g + l * C0;
  const float* w1 = W1g + l * (C0 * C1);
  const float* B1 = b1g + l * C1;

  float h[C0];
#pragma unroll
  for (int c = 0; c < C0; c++) h[c] = B0[c];
#pragma unroll
  for (int k = 0; k < IN_DIM; k++) {
#pragma unroll
    for (int c = 0; c < C0; c++) h[c] = fmaf(x[k], w0[k * C0 + c], h[c]);
  }
#pragma unroll
  for (int c = 0; c < C0; c++) h[c] = h[c] >= 0.f ? h[c] : 0.2f * h[c];

  float o[C1];
#pragma unroll
  for (int c = 0; c < C1; c++) o[c] = B1[c];
#pragma unroll
  for (int k = 0; k < C0; k++) {
#pragma unroll
    for (int c = 0; c < C1; c++) o[c] = fmaf(h[k], w1[k * C1 + c], o[c]);
  }
#pragma unroll
  for (int c = 0; c < C1; c++) o[c] = o[c] >= 0.f ? o[c] : 0.2f * o[c];

  // ---- chunked LDS transpose epilogue: 64 rows (8KB) at a time ----
  __shared__ float obuf[64 * 32];
  int wv = T >> 6;
  int row = T >> 2;          // 0..63 (reader role)
  int q = (T & 3) * 8;       // reader column start
#pragma unroll
  for (int c = 0; c < 4; c++) {
    if (wv == c) {
      // wave c writes its 64 rows, XOR-swizzled (16B-aligned preserved)
#pragma unroll
      for (int cq = 0; cq < 32; cq += 4) {
        int ad = lane * 32 + (cq ^ ((lane & 7) << 2));
        float4 v = {o[cq], o[cq + 1], o[cq + 2], o[cq + 3]};
        *(float4*)&obuf[ad] = v;
      }
    }
    __syncthreads();
    int slot_r = blockbase + c * 64 + row;
    if (slot_r < end) {
      int p = perm[slot_r];
      int sw = (row & 7) << 2;
      float4 v0 = *(const float4*)&obuf[row * 32 + (q ^ sw)];
      float4 v1 = *(const float4*)&obuf[row * 32 + ((q + 4) ^ sw)];
      float* dst = out + (size_t)p * C1 + q;
      *(float4*)dst = v0;
      *(float4*)(dst + 4) = v1;
    }
    if (c < 3) __syncthreads();
  }
}

extern "C" void kernel_launch(void* const* d_in, const int* in_sizes, int n_in,
                              void* d_out, int out_size, void* d_ws, size_t ws_size,
                              hipStream_t stream) {
  const float* inp = (const float*)d_in[0];
  const int* idx   = (const int*)d_in[1];
  const float* W0  = (const float*)d_in[2];
  const float* b0  = (const float*)d_in[3];
  const float* W1  = (const float*)d_in[4];
  const float* b1  = (const float*)d_in[5];
  float* out = (float*)d_out;
  int E = in_sizes[1];

  int nBlk = (E + 255) / 256 + L;  // upper bound on padded 256-blocks
  size_t slots = (size_t)nBlk * 256;

  int* ws = (int*)d_ws;
  int* blockCounts = ws;                       // GHIST*L
  int* cursor      = blockCounts + GHIST * L;  // GHIST*L
  int* endArr      = cursor + GHIST * L;       // L
  int* baseArr     = endArr + L;               // L+1
  int* perm        = baseArr + (L + 1);        // slots
  size_t ints = (size_t)2 * GHIST * L + L + (L + 1) + slots;
  ints = (ints + 3) & ~(size_t)3;              // 16B-align xb
  float* xb = (float*)(ws + ints);             // slots * 8 floats
  size_t need = ints * 4 + slots * 8 * 4;
  bool use_xb = ws_size >= need;

  k_hist<<<GHIST, 256, 0, stream>>>(idx, E, blockCounts);
  k_scan<<<1, 256, 0, stream>>>(blockCounts, cursor, endArr, baseArr);
  k_scatter<<<GHIST, 256, 0, stream>>>(idx, inp, E, cursor, perm, xb);

  if (use_xb) {
    k_compute<true><<<nBlk, 256, 0, stream>>>(xb, inp, W0, b0, W1, b1,
                                              perm, baseArr, endArr, out);
  } else {
    k_compute<false><<<nBlk, 256, 0, stream>>>(nullptr, inp, W0, b0, W1, b1,
                                               perm, baseArr, endArr, out);
  }
}